// Round 16
// baseline (99.702 us; speedup 1.0000x reference)
//
#include <hip/hip_runtime.h>
#include <hip/hip_bf16.h>
#include <math.h>

#define D_MODEL 1024
#define TLEN    2048

typedef __attribute__((ext_vector_type(8))) short short8;
typedef __attribute__((ext_vector_type(4))) float f32x4;

static __device__ __forceinline__ unsigned short f2bf(float f) {
    __hip_bfloat16 h = __float2bfloat16(f);
    return __builtin_bit_cast(unsigned short, h);
}
static __device__ __forceinline__ float bf2f(unsigned short u) {
    unsigned int x = ((unsigned int)u) << 16;
    return __builtin_bit_cast(float, x);
}

// ---------------------------------------------------------------------------
// Kernel 0: pack W fp32 [384][1024] -> plain bf16 row-major [384][1024].
// (B is consumed from registers now — no swizzle needed.)
// ---------------------------------------------------------------------------
__global__ __launch_bounds__(256) void pack_w(const float* __restrict__ W,
                                              unsigned short* __restrict__ wb) {
    const int id = blockIdx.x * 256 + threadIdx.x;   // 49152 = 384*128
    const int h  = id >> 7;
    const int k0 = (id & 127) * 8;
    const float4 a = *(const float4*)&W[(size_t)h * D_MODEL + k0];
    const float4 b = *(const float4*)&W[(size_t)h * D_MODEL + k0 + 4];
    short8 v;
    v[0] = (short)f2bf(a.x); v[1] = (short)f2bf(a.y);
    v[2] = (short)f2bf(a.z); v[3] = (short)f2bf(a.w);
    v[4] = (short)f2bf(b.x); v[5] = (short)f2bf(b.y);
    v[6] = (short)f2bf(b.z); v[7] = (short)f2bf(b.w);
    *(short8*)&wb[(size_t)h * D_MODEL + k0] = v;
}

// ---------------------------------------------------------------------------
// Kernel 1: qkv = x @ W^T. BM=64, BN=128, BK=64, grid (256,3) — r10 tile, but:
//  * B-fragments live in REGISTERS, prefetched one full k-step ahead from L2
//    (W is 768 KB bf16, L2-resident). No LDS for B, no gload_lds.
//  * Only A staged in LDS, double-buffered, written from prefetched x regs —
//    so the per-step __syncthreads drain has nothing left to wait for.
// 4 waves (2m x 2n), 16 MFMA/wave/step. Q panel pre-scaled by 1/sqrt(128).
// ---------------------------------------------------------------------------
__global__ __launch_bounds__(256, 3) void qkv_gemm(const float* __restrict__ x,
                                                   const unsigned short* __restrict__ wb,
                                                   unsigned short* __restrict__ qk,
                                                   unsigned short* __restrict__ vt) {
    __shared__ unsigned short As[2][64][88];   // dbuf, padded rows (r10 layout)

    const int tid  = threadIdx.x;
    const int lane = tid & 63;
    const int w    = tid >> 6;
    const int wm   = w >> 1, wn = w & 1;
    const int cc   = lane & 15, g = lane >> 4;
    const int row0 = blockIdx.x * 64;
    const int np   = blockIdx.y;

    const int xr  = tid >> 2;          // 0..63
    const int xc0 = (tid & 3) * 16;    // 0,16,32,48 (shorts)

    const f32x4 zero = {0.f, 0.f, 0.f, 0.f};
    f32x4 acc[2][4];
#pragma unroll
    for (int i = 0; i < 2; ++i)
#pragma unroll
        for (int j = 0; j < 4; ++j) acc[i][j] = zero;

    const float* xrow = x + (size_t)(row0 + xr) * D_MODEL + xc0;
    float4 xa[4];
#pragma unroll
    for (int i = 0; i < 4; ++i) xa[i] = *(const float4*)(xrow + i * 4);

    // per-lane B pointers: row h = np*128 + wn*64 + nt*16 + cc, col base g*8
    const unsigned short* bptr[4];
#pragma unroll
    for (int nt = 0; nt < 4; ++nt)
        bptr[nt] = wb + (size_t)(np * 128 + wn * 64 + nt * 16 + cc) * D_MODEL + g * 8;

    // B-frag double buffer in registers; prologue loads step 0
    short8 bq[2][2][4];
#pragma unroll
    for (int ks = 0; ks < 2; ++ks)
#pragma unroll
        for (int nt = 0; nt < 4; ++nt)
            bq[0][ks][nt] = *(const short8*)(bptr[nt] + ks * 32);

    for (int kt = 0; kt < 16; ++kt) {
        const int cur = kt & 1;
        // stage As[cur] from prefetched x regs
        {
            short8 s0, s1;
            s0[0] = (short)f2bf(xa[0].x); s0[1] = (short)f2bf(xa[0].y);
            s0[2] = (short)f2bf(xa[0].z); s0[3] = (short)f2bf(xa[0].w);
            s0[4] = (short)f2bf(xa[1].x); s0[5] = (short)f2bf(xa[1].y);
            s0[6] = (short)f2bf(xa[1].z); s0[7] = (short)f2bf(xa[1].w);
            s1[0] = (short)f2bf(xa[2].x); s1[1] = (short)f2bf(xa[2].y);
            s1[2] = (short)f2bf(xa[2].z); s1[3] = (short)f2bf(xa[2].w);
            s1[4] = (short)f2bf(xa[3].x); s1[5] = (short)f2bf(xa[3].y);
            s1[6] = (short)f2bf(xa[3].z); s1[7] = (short)f2bf(xa[3].w);
            *(short8*)&As[cur][xr][xc0]     = s0;
            *(short8*)&As[cur][xr][xc0 + 8] = s1;
        }
        __syncthreads();   // lgkm: As[cur] visible; vmcnt: drains only loads due now

        // prefetch B(kt+1) into the other reg set + x(kt+1) — a full step of slack
        if (kt + 1 < 16) {
#pragma unroll
            for (int ks = 0; ks < 2; ++ks)
#pragma unroll
                for (int nt = 0; nt < 4; ++nt)
                    bq[cur ^ 1][ks][nt] =
                        *(const short8*)(bptr[nt] + (kt + 1) * 64 + ks * 32);
#pragma unroll
            for (int i = 0; i < 4; ++i)
                xa[i] = *(const float4*)(xrow + (kt + 1) * 64 + i * 4);
        }

        short8 af[2][2];
#pragma unroll
        for (int ks = 0; ks < 2; ++ks)
#pragma unroll
            for (int mt = 0; mt < 2; ++mt)
                af[ks][mt] = *(const short8*)&As[cur][wm * 32 + mt * 16 + cc][ks * 32 + g * 8];

        __builtin_amdgcn_s_setprio(1);
#pragma unroll
        for (int ks = 0; ks < 2; ++ks)
#pragma unroll
            for (int mt = 0; mt < 2; ++mt)
#pragma unroll
                for (int nt = 0; nt < 4; ++nt)
                    acc[mt][nt] = __builtin_amdgcn_mfma_f32_16x16x32_bf16(
                        af[ks][mt], bq[cur][ks][nt], acc[mt][nt], 0, 0, 0);
        __builtin_amdgcn_s_setprio(0);
    }

    const int bb  = row0 >> 11;
    const int tr0 = row0 & 2047;
    const float qs = (np == 0) ? 0.08838834764831845f : 1.0f;
#pragma unroll
    for (int mt = 0; mt < 2; ++mt)
#pragma unroll
        for (int nt = 0; nt < 4; ++nt) {
            const int colp = wn * 64 + nt * 16;
            if (np < 2) {
#pragma unroll
                for (int r = 0; r < 4; ++r) {
                    const int row = row0 + wm * 32 + mt * 16 + g * 4 + r;
                    qk[(size_t)row * 256 + np * 128 + colp + cc] = f2bf(acc[mt][nt][r] * qs);
                }
            } else {
                const int d    = colp + cc;
                const int trow = tr0 + wm * 32 + mt * 16 + g * 4;
                ushort4 u;
                u.x = f2bf(acc[mt][nt][0]);
                u.y = f2bf(acc[mt][nt][1]);
                u.z = f2bf(acc[mt][nt][2]);
                u.w = f2bf(acc[mt][nt][3]);
                *(ushort4*)&vt[((size_t)(bb * 128 + d)) * TLEN + trow] = u;
            }
        }
}

// ---------------------------------------------------------------------------
// Kernel 2: attention partial (exact r7/r10 version).
// ---------------------------------------------------------------------------
__global__ __launch_bounds__(256, 3) void attn_part(const unsigned short* __restrict__ qk,
                                                    const unsigned short* __restrict__ vt,
                                                    unsigned short* __restrict__ po,
                                                    float2* __restrict__ ml) {
    __shared__ unsigned short Ks[64 * 128];
    __shared__ unsigned short Vs[128 * 64];
    __shared__ unsigned short Ps[4][16][72];

    const int tid  = threadIdx.x;
    const int lane = tid & 63;
    const int w    = tid >> 6;
    const int cc   = lane & 15, g = lane >> 4;
    const int bx   = blockIdx.x;
    const int qt   = 31 - (bx / 3);
    const int ggg  = bx % 3;
    const int b    = blockIdx.y;
    const int q0   = qt * 64;
    const int slot = (b * 32 + qt) * 3 + ggg;
    const int n    = qt + 1;
    const int cnt  = (n > ggg) ? ((n - ggg + 2) / 3) : 0;

    if (cnt == 0) {
#pragma unroll
        for (int nt = 0; nt < 8; ++nt)
#pragma unroll
            for (int r = 0; r < 4; ++r)
                po[((size_t)slot * 64 + w * 16 + g * 4 + r) * 128 + nt * 16 + cc] = 0;
        if (g == 0) ml[slot * 64 + w * 16 + cc] = make_float2(-INFINITY, 0.f);
        return;
    }

    short8 qf[4];
    {
        const unsigned short* qb =
            qk + ((size_t)(b * TLEN + q0 + w * 16 + cc)) * 256 + g * 8;
#pragma unroll
        for (int kt = 0; kt < 4; ++kt) qf[kt] = *(const short8*)(qb + kt * 32);
    }

    const f32x4 zero = {0.f, 0.f, 0.f, 0.f};
    f32x4 o[8];
#pragma unroll
    for (int nt = 0; nt < 8; ++nt) o[nt] = zero;
    float mrun = -INFINITY, lrun = 0.f;

    int koff[4], voff[2];
#pragma unroll
    for (int kt = 0; kt < 4; ++kt)
        koff[kt] = cc * 128 + (((kt * 4 + g) ^ (cc & 7)) << 3);
#pragma unroll
    for (int ks = 0; ks < 2; ++ks)
        voff[ks] = cc * 64 + (((ks * 4 + g) ^ (cc & 7)) << 3);

    const int kRow = tid >> 2;
    const int kG0  = (tid & 3) * 4;
    const int vRow = tid >> 1;
    const int vG0  = (tid & 1) * 4;
    const unsigned short* kgp = qk + ((size_t)(b * TLEN + kRow)) * 256 + 128 + kG0 * 8;
    const unsigned short* vgp = vt + ((size_t)(b * 128 + vRow)) * TLEN + vG0 * 8;

    short8 kr[4], vr[4];
#pragma unroll
    for (int i = 0; i < 4; ++i) kr[i] = *(const short8*)(kgp + (size_t)ggg * 16384 + i * 8);
#pragma unroll
    for (int i = 0; i < 4; ++i) vr[i] = *(const short8*)(vgp + ggg * 64 + i * 8);

    for (int s = 0; s < cnt; ++s) {
        const int t  = 3 * s + ggg;
        const int j0 = t * 64;
        __syncthreads();
#pragma unroll
        for (int i = 0; i < 4; ++i) {
            *(short8*)&Ks[kRow * 128 + (((kG0 + i) ^ (kRow & 7)) << 3)] = kr[i];
            *(short8*)&Vs[vRow * 64  + (((vG0 + i) ^ (vRow & 7)) << 3)] = vr[i];
        }
        __syncthreads();
        if (s + 1 < cnt) {
            const int tn = t + 3;
#pragma unroll
            for (int i = 0; i < 4; ++i) kr[i] = *(const short8*)(kgp + (size_t)tn * 16384 + i * 8);
#pragma unroll
            for (int i = 0; i < 4; ++i) vr[i] = *(const short8*)(vgp + tn * 64 + i * 8);
        }

        f32x4 st[4];
#pragma unroll
        for (int jt = 0; jt < 4; ++jt) st[jt] = zero;
        __builtin_amdgcn_s_setprio(1);
#pragma unroll
        for (int kt = 0; kt < 4; ++kt)
#pragma unroll
            for (int jt = 0; jt < 4; ++jt) {
                const short8 kf = *(const short8*)&Ks[koff[kt] + jt * 2048];
                st[jt] = __builtin_amdgcn_mfma_f32_16x16x32_bf16(kf, qf[kt], st[jt], 0, 0, 0);
            }
        __builtin_amdgcn_s_setprio(0);

        if (t == qt) {
            const int qg = q0 + w * 16 + cc;
            const int jb = j0 + 4 * g;
#pragma unroll
            for (int jt = 0; jt < 4; ++jt)
#pragma unroll
                for (int r = 0; r < 4; ++r)
                    if (jb + jt * 16 + r > qg) st[jt][r] = -INFINITY;
        }
        float pmax = -INFINITY;
#pragma unroll
        for (int jt = 0; jt < 4; ++jt) {
            const float a = fmaxf(st[jt][0], st[jt][1]);
            const float c = fmaxf(st[jt][2], st[jt][3]);
            pmax = fmaxf(pmax, fmaxf(a, c));
        }
        pmax = fmaxf(pmax, __shfl_xor(pmax, 16));
        pmax = fmaxf(pmax, __shfl_xor(pmax, 32));

        if (!__all(pmax <= mrun + 8.f)) {
            const float newm  = fmaxf(mrun, pmax);
            const float alpha = __expf(mrun - newm);
            mrun = newm;
            lrun *= alpha;
            float arow[4];
#pragma unroll
            for (int r = 0; r < 4; ++r) arow[r] = __shfl(alpha, 20 * g + r);
#pragma unroll
            for (int nt = 0; nt < 8; ++nt)
#pragma unroll
                for (int r = 0; r < 4; ++r) o[nt][r] *= arow[r];
        }

        float rs = 0.f;
#pragma unroll
        for (int jt = 0; jt < 4; ++jt) {
            const float p0 = __expf(st[jt][0] - mrun);
            const float p1 = __expf(st[jt][1] - mrun);
            const float p2 = __expf(st[jt][2] - mrun);
            const float p3 = __expf(st[jt][3] - mrun);
            rs += (p0 + p1) + (p2 + p3);
            uint2 pw;
            pw.x = (unsigned int)f2bf(p0) | ((unsigned int)f2bf(p1) << 16);
            pw.y = (unsigned int)f2bf(p2) | ((unsigned int)f2bf(p3) << 16);
            *(uint2*)&Ps[w][cc][jt * 16 + 4 * g] = pw;
        }
        rs += __shfl_xor(rs, 16);
        rs += __shfl_xor(rs, 32);
        lrun += rs;

        asm volatile("s_waitcnt lgkmcnt(0)" ::: "memory");
        __builtin_amdgcn_sched_barrier(0);

        __builtin_amdgcn_s_setprio(1);
#pragma unroll
        for (int ks = 0; ks < 2; ++ks) {
            const short8 pa = *(const short8*)&Ps[w][cc][ks * 32 + g * 8];
#pragma unroll
            for (int nt = 0; nt < 8; ++nt) {
                const short8 vf = *(const short8*)&Vs[voff[ks] + nt * 1024];
                o[nt] = __builtin_amdgcn_mfma_f32_16x16x32_bf16(pa, vf, o[nt], 0, 0, 0);
            }
        }
        __builtin_amdgcn_s_setprio(0);
    }

#pragma unroll
    for (int nt = 0; nt < 8; ++nt)
#pragma unroll
        for (int r = 0; r < 4; ++r)
            po[((size_t)slot * 64 + w * 16 + g * 4 + r) * 128 + nt * 16 + cc] =
                f2bf(o[nt][r]);
    if (g == 0) ml[slot * 64 + w * 16 + cc] = make_float2(mrun, lrun);
}

// ---------------------------------------------------------------------------
// Kernel 3: merge 3 partials per q-row (exact r10 version).
// ---------------------------------------------------------------------------
__global__ __launch_bounds__(256) void attn_merge(const unsigned short* __restrict__ po,
                                                  const float2* __restrict__ ml,
                                                  float* __restrict__ out) {
    const int bq   = blockIdx.x;
    const int row  = threadIdx.x >> 2;
    const int cs   = (threadIdx.x & 3) * 32;
    const int slot = bq * 3;

    const float2 ml0 = ml[(size_t)(slot + 0) * 64 + row];
    const float2 ml1 = ml[(size_t)(slot + 1) * 64 + row];
    const float2 ml2 = ml[(size_t)(slot + 2) * 64 + row];
    const float M  = fmaxf(fmaxf(ml0.x, ml1.x), ml2.x);
    float e0 = __expf(ml0.x - M);
    float e1 = __expf(ml1.x - M);
    float e2 = __expf(ml2.x - M);
    const float inv = 1.f / (ml0.y * e0 + ml1.y * e1 + ml2.y * e2);
    e0 *= inv; e1 *= inv; e2 *= inv;

    const unsigned short* p0 = po + ((size_t)(slot + 0) * 64 + row) * 128 + cs;
    const unsigned short* p1 = po + ((size_t)(slot + 1) * 64 + row) * 128 + cs;
    const unsigned short* p2 = po + ((size_t)(slot + 2) * 64 + row) * 128 + cs;
    float* op = out + ((size_t)bq * 64 + row) * 128 + cs;

#pragma unroll
    for (int i = 0; i < 4; ++i) {
        const short8 a = *(const short8*)(p0 + i * 8);
        const short8 b = *(const short8*)(p1 + i * 8);
        const short8 c = *(const short8*)(p2 + i * 8);
        float4 o0, o1;
        o0.x = bf2f((unsigned short)a[0]) * e0 + bf2f((unsigned short)b[0]) * e1 + bf2f((unsigned short)c[0]) * e2;
        o0.y = bf2f((unsigned short)a[1]) * e0 + bf2f((unsigned short)b[1]) * e1 + bf2f((unsigned short)c[1]) * e2;
        o0.z = bf2f((unsigned short)a[2]) * e0 + bf2f((unsigned short)b[2]) * e1 + bf2f((unsigned short)c[2]) * e2;
        o0.w = bf2f((unsigned short)a[3]) * e0 + bf2f((unsigned short)b[3]) * e1 + bf2f((unsigned short)c[3]) * e2;
        o1.x = bf2f((unsigned short)a[4]) * e0 + bf2f((unsigned short)b[4]) * e1 + bf2f((unsigned short)c[4]) * e2;
        o1.y = bf2f((unsigned short)a[5]) * e0 + bf2f((unsigned short)b[5]) * e1 + bf2f((unsigned short)c[5]) * e2;
        o1.z = bf2f((unsigned short)a[6]) * e0 + bf2f((unsigned short)b[6]) * e1 + bf2f((unsigned short)c[6]) * e2;
        o1.w = bf2f((unsigned short)a[7]) * e0 + bf2f((unsigned short)b[7]) * e1 + bf2f((unsigned short)c[7]) * e2;
        *(float4*)(op + i * 8)     = o0;
        *(float4*)(op + i * 8 + 4) = o1;
    }
}

extern "C" void kernel_launch(void* const* d_in, const int* in_sizes, int n_in,
                              void* d_out, int out_size, void* d_ws, size_t ws_size,
                              hipStream_t stream) {
    (void)in_sizes; (void)n_in; (void)out_size; (void)ws_size;
    const float* x = (const float*)d_in[0];      // (8,2048,1024) f32
    const float* W = (const float*)d_in[1];      // (384,1024) f32
    float* out = (float*)d_out;                  // (8,2048,128) f32

    unsigned short* qkbf = (unsigned short*)d_ws;           // [16384][256] bf16
    unsigned short* vtbf = qkbf + (size_t)16384 * 256;      // [8][128][2048] bf16
    unsigned short* wbbf = vtbf + (size_t)8 * 128 * 2048;   // W bf16, 768 KB
    unsigned short* pobf = wbbf + (size_t)384 * 1024;                // partials o
    float2*         mlf  = (float2*)(pobf + (size_t)768 * 64 * 128); // partials m,l

    pack_w<<<dim3(192), 256, 0, stream>>>(W, wbbf);
    qkv_gemm<<<dim3(256, 3), 256, 0, stream>>>(x, wbbf, qkbf, vtbf);
    attn_part<<<dim3(96, 8), 256, 0, stream>>>(qkbf, vtbf, pobf, mlf);
    attn_merge<<<dim3(256), 256, 0, stream>>>(pobf, mlf, out);
}

// Round 17
// 75.282 us; speedup vs baseline: 1.3244x; 1.3244x over previous
//
#include <hip/hip_runtime.h>
#include <hip/hip_bf16.h>
#include <math.h>

#define D_MODEL 1024
#define TLEN    2048

typedef __attribute__((ext_vector_type(8))) short short8;
typedef __attribute__((ext_vector_type(4))) float f32x4;

static __device__ __forceinline__ unsigned short f2bf(float f) {
    __hip_bfloat16 h = __float2bfloat16(f);
    return __builtin_bit_cast(unsigned short, h);
}
static __device__ __forceinline__ float bf2f(unsigned short u) {
    unsigned int x = ((unsigned int)u) << 16;
    return __builtin_bit_cast(float, x);
}
static __device__ __forceinline__ void lds_cp16(void* lds, const void* g) {
    __builtin_amdgcn_global_load_lds(
        (const __attribute__((address_space(1))) unsigned int*)g,
        (__attribute__((address_space(3))) unsigned int*)lds, 16, 0, 0);
}

// ---------------------------------------------------------------------------
// Kernel 0 (exact r10): pack W fp32 [384][1024] -> wt bf16 [np3][kt16][h128][k64]
// swizzled (8-short k-group XOR h&7).
// ---------------------------------------------------------------------------
__global__ __launch_bounds__(256) void pack_w(const float* __restrict__ W,
                                              unsigned short* __restrict__ wt) {
    const int id = blockIdx.x * 256 + threadIdx.x;
    const int h  = id >> 7;
    const int kg = id & 127;
    const int k0 = kg * 8;
    const int kt = k0 >> 6;
    const int kin = k0 & 63;
    const int np = h >> 7;
    const int hp = h & 127;
    const float4 a = *(const float4*)&W[(size_t)h * D_MODEL + k0];
    const float4 b = *(const float4*)&W[(size_t)h * D_MODEL + k0 + 4];
    short8 v;
    v[0] = (short)f2bf(a.x); v[1] = (short)f2bf(a.y);
    v[2] = (short)f2bf(a.z); v[3] = (short)f2bf(a.w);
    v[4] = (short)f2bf(b.x); v[5] = (short)f2bf(b.y);
    v[6] = (short)f2bf(b.z); v[7] = (short)f2bf(b.w);
    const size_t dst = ((size_t)(np * 16 + kt) * 128 + hp) * 64 + (kin ^ ((hp & 7) * 8));
    *(short8*)&wt[dst] = v;
}

// ---------------------------------------------------------------------------
// Kernel 1 (r10 structure, proven ~30us): BM=64, BN=128, BK=64, 4 waves,
// 27.6 KB LDS. ONLY change vs r10: grid is (3,256) with np=blockIdx.x,
// bx=blockIdx.y -> panel siblings of a row tile dispatch adjacently
// (x tile L2/L3-hot when re-read). Q panel pre-scaled by 1/sqrt(128).
// ---------------------------------------------------------------------------
__global__ __launch_bounds__(256, 4) void qkv_gemm(const float* __restrict__ x,
                                                   const unsigned short* __restrict__ wt,
                                                   unsigned short* __restrict__ qk,
                                                   unsigned short* __restrict__ vt) {
    __shared__ unsigned short As[64][88];
    __shared__ unsigned short Bs[128 * 64];

    const int tid  = threadIdx.x;
    const int lane = tid & 63;
    const int w    = tid >> 6;
    const int wm   = w >> 1, wn = w & 1;
    const int cc   = lane & 15, g = lane >> 4;
    const int np   = blockIdx.x;               // 0..2 (fastest: siblings adjacent)
    const int row0 = blockIdx.y * 64;          // 0..255 row tiles

    const int xr  = tid >> 2;
    const int xc0 = (tid & 3) * 16;

    const f32x4 zero = {0.f, 0.f, 0.f, 0.f};
    f32x4 acc[2][4];
#pragma unroll
    for (int i = 0; i < 2; ++i)
#pragma unroll
        for (int j = 0; j < 4; ++j) acc[i][j] = zero;

    const float* xrow = x + (size_t)(row0 + xr) * D_MODEL + xc0;
    float4 xa[4];
#pragma unroll
    for (int i = 0; i < 4; ++i) xa[i] = *(const float4*)(xrow + i * 4);

    const unsigned short* wtile0 =
        wt + (size_t)np * 16 * 128 * 64 + (w * 4 * 1024 + lane * 16) / 2;
    unsigned short* bdst = Bs + (w * 4 * 1024) / 2;

    for (int kt = 0; kt < 16; ++kt) {
        __syncthreads();
        {
            short8 s0, s1;
            s0[0] = (short)f2bf(xa[0].x); s0[1] = (short)f2bf(xa[0].y);
            s0[2] = (short)f2bf(xa[0].z); s0[3] = (short)f2bf(xa[0].w);
            s0[4] = (short)f2bf(xa[1].x); s0[5] = (short)f2bf(xa[1].y);
            s0[6] = (short)f2bf(xa[1].z); s0[7] = (short)f2bf(xa[1].w);
            s1[0] = (short)f2bf(xa[2].x); s1[1] = (short)f2bf(xa[2].y);
            s1[2] = (short)f2bf(xa[2].z); s1[3] = (short)f2bf(xa[2].w);
            s1[4] = (short)f2bf(xa[3].x); s1[5] = (short)f2bf(xa[3].y);
            s1[6] = (short)f2bf(xa[3].z); s1[7] = (short)f2bf(xa[3].w);
            *(short8*)&As[xr][xc0]     = s0;
            *(short8*)&As[xr][xc0 + 8] = s1;
        }
        const unsigned short* wtk = wtile0 + (size_t)kt * 128 * 64;
#pragma unroll
        for (int i = 0; i < 4; ++i)
            lds_cp16(bdst + i * 512, wtk + i * 512);
        __syncthreads();

        short8 af[2][2], bf[2][4];
#pragma unroll
        for (int ks = 0; ks < 2; ++ks) {
#pragma unroll
            for (int mt = 0; mt < 2; ++mt)
                af[ks][mt] = *(const short8*)&As[wm * 32 + mt * 16 + cc][ks * 32 + g * 8];
#pragma unroll
            for (int nt = 0; nt < 4; ++nt) {
                const int h = wn * 64 + nt * 16 + cc;
                bf[ks][nt] = *(const short8*)&Bs[h * 64 + (((ks * 4 + g) ^ (h & 7)) << 3)];
            }
        }
        if (kt + 1 < 16) {
#pragma unroll
            for (int i = 0; i < 4; ++i)
                xa[i] = *(const float4*)(xrow + (kt + 1) * 64 + i * 4);
        }
        __builtin_amdgcn_s_setprio(1);
#pragma unroll
        for (int ks = 0; ks < 2; ++ks)
#pragma unroll
            for (int mt = 0; mt < 2; ++mt)
#pragma unroll
                for (int nt = 0; nt < 4; ++nt)
                    acc[mt][nt] = __builtin_amdgcn_mfma_f32_16x16x32_bf16(
                        af[ks][mt], bf[ks][nt], acc[mt][nt], 0, 0, 0);
        __builtin_amdgcn_s_setprio(0);
    }

    const int bb  = row0 >> 11;
    const int tr0 = row0 & 2047;
    const float qs = (np == 0) ? 0.08838834764831845f : 1.0f;
#pragma unroll
    for (int mt = 0; mt < 2; ++mt)
#pragma unroll
        for (int nt = 0; nt < 4; ++nt) {
            const int colp = wn * 64 + nt * 16;
            if (np < 2) {
#pragma unroll
                for (int r = 0; r < 4; ++r) {
                    const int row = row0 + wm * 32 + mt * 16 + g * 4 + r;
                    qk[(size_t)row * 256 + np * 128 + colp + cc] = f2bf(acc[mt][nt][r] * qs);
                }
            } else {
                const int d    = colp + cc;
                const int trow = tr0 + wm * 32 + mt * 16 + g * 4;
                ushort4 u;
                u.x = f2bf(acc[mt][nt][0]);
                u.y = f2bf(acc[mt][nt][1]);
                u.z = f2bf(acc[mt][nt][2]);
                u.w = f2bf(acc[mt][nt][3]);
                *(ushort4*)&vt[((size_t)(bb * 128 + d)) * TLEN + trow] = u;
            }
        }
}

// ---------------------------------------------------------------------------
// Kernel 2: attention partial (exact r7/r10 version — proven ~25 us).
// ---------------------------------------------------------------------------
__global__ __launch_bounds__(256, 3) void attn_part(const unsigned short* __restrict__ qk,
                                                    const unsigned short* __restrict__ vt,
                                                    unsigned short* __restrict__ po,
                                                    float2* __restrict__ ml) {
    __shared__ unsigned short Ks[64 * 128];
    __shared__ unsigned short Vs[128 * 64];
    __shared__ unsigned short Ps[4][16][72];

    const int tid  = threadIdx.x;
    const int lane = tid & 63;
    const int w    = tid >> 6;
    const int cc   = lane & 15, g = lane >> 4;
    const int bx   = blockIdx.x;
    const int qt   = 31 - (bx / 3);
    const int ggg  = bx % 3;
    const int b    = blockIdx.y;
    const int q0   = qt * 64;
    const int slot = (b * 32 + qt) * 3 + ggg;
    const int n    = qt + 1;
    const int cnt  = (n > ggg) ? ((n - ggg + 2) / 3) : 0;

    if (cnt == 0) {
#pragma unroll
        for (int nt = 0; nt < 8; ++nt)
#pragma unroll
            for (int r = 0; r < 4; ++r)
                po[((size_t)slot * 64 + w * 16 + g * 4 + r) * 128 + nt * 16 + cc] = 0;
        if (g == 0) ml[slot * 64 + w * 16 + cc] = make_float2(-INFINITY, 0.f);
        return;
    }

    short8 qf[4];
    {
        const unsigned short* qb =
            qk + ((size_t)(b * TLEN + q0 + w * 16 + cc)) * 256 + g * 8;
#pragma unroll
        for (int kt = 0; kt < 4; ++kt) qf[kt] = *(const short8*)(qb + kt * 32);
    }

    const f32x4 zero = {0.f, 0.f, 0.f, 0.f};
    f32x4 o[8];
#pragma unroll
    for (int nt = 0; nt < 8; ++nt) o[nt] = zero;
    float mrun = -INFINITY, lrun = 0.f;

    int koff[4], voff[2];
#pragma unroll
    for (int kt = 0; kt < 4; ++kt)
        koff[kt] = cc * 128 + (((kt * 4 + g) ^ (cc & 7)) << 3);
#pragma unroll
    for (int ks = 0; ks < 2; ++ks)
        voff[ks] = cc * 64 + (((ks * 4 + g) ^ (cc & 7)) << 3);

    const int kRow = tid >> 2;
    const int kG0  = (tid & 3) * 4;
    const int vRow = tid >> 1;
    const int vG0  = (tid & 1) * 4;
    const unsigned short* kgp = qk + ((size_t)(b * TLEN + kRow)) * 256 + 128 + kG0 * 8;
    const unsigned short* vgp = vt + ((size_t)(b * 128 + vRow)) * TLEN + vG0 * 8;

    short8 kr[4], vr[4];
#pragma unroll
    for (int i = 0; i < 4; ++i) kr[i] = *(const short8*)(kgp + (size_t)ggg * 16384 + i * 8);
#pragma unroll
    for (int i = 0; i < 4; ++i) vr[i] = *(const short8*)(vgp + ggg * 64 + i * 8);

    for (int s = 0; s < cnt; ++s) {
        const int t  = 3 * s + ggg;
        const int j0 = t * 64;
        __syncthreads();
#pragma unroll
        for (int i = 0; i < 4; ++i) {
            *(short8*)&Ks[kRow * 128 + (((kG0 + i) ^ (kRow & 7)) << 3)] = kr[i];
            *(short8*)&Vs[vRow * 64  + (((vG0 + i) ^ (vRow & 7)) << 3)] = vr[i];
        }
        __syncthreads();
        if (s + 1 < cnt) {
            const int tn = t + 3;
#pragma unroll
            for (int i = 0; i < 4; ++i) kr[i] = *(const short8*)(kgp + (size_t)tn * 16384 + i * 8);
#pragma unroll
            for (int i = 0; i < 4; ++i) vr[i] = *(const short8*)(vgp + tn * 64 + i * 8);
        }

        f32x4 st[4];
#pragma unroll
        for (int jt = 0; jt < 4; ++jt) st[jt] = zero;
        __builtin_amdgcn_s_setprio(1);
#pragma unroll
        for (int kt = 0; kt < 4; ++kt)
#pragma unroll
            for (int jt = 0; jt < 4; ++jt) {
                const short8 kf = *(const short8*)&Ks[koff[kt] + jt * 2048];
                st[jt] = __builtin_amdgcn_mfma_f32_16x16x32_bf16(kf, qf[kt], st[jt], 0, 0, 0);
            }
        __builtin_amdgcn_s_setprio(0);

        if (t == qt) {
            const int qg = q0 + w * 16 + cc;
            const int jb = j0 + 4 * g;
#pragma unroll
            for (int jt = 0; jt < 4; ++jt)
#pragma unroll
                for (int r = 0; r < 4; ++r)
                    if (jb + jt * 16 + r > qg) st[jt][r] = -INFINITY;
        }
        float pmax = -INFINITY;
#pragma unroll
        for (int jt = 0; jt < 4; ++jt) {
            const float a = fmaxf(st[jt][0], st[jt][1]);
            const float c = fmaxf(st[jt][2], st[jt][3]);
            pmax = fmaxf(pmax, fmaxf(a, c));
        }
        pmax = fmaxf(pmax, __shfl_xor(pmax, 16));
        pmax = fmaxf(pmax, __shfl_xor(pmax, 32));

        if (!__all(pmax <= mrun + 8.f)) {
            const float newm  = fmaxf(mrun, pmax);
            const float alpha = __expf(mrun - newm);
            mrun = newm;
            lrun *= alpha;
            float arow[4];
#pragma unroll
            for (int r = 0; r < 4; ++r) arow[r] = __shfl(alpha, 20 * g + r);
#pragma unroll
            for (int nt = 0; nt < 8; ++nt)
#pragma unroll
                for (int r = 0; r < 4; ++r) o[nt][r] *= arow[r];
        }

        float rs = 0.f;
#pragma unroll
        for (int jt = 0; jt < 4; ++jt) {
            const float p0 = __expf(st[jt][0] - mrun);
            const float p1 = __expf(st[jt][1] - mrun);
            const float p2 = __expf(st[jt][2] - mrun);
            const float p3 = __expf(st[jt][3] - mrun);
            rs += (p0 + p1) + (p2 + p3);
            uint2 pw;
            pw.x = (unsigned int)f2bf(p0) | ((unsigned int)f2bf(p1) << 16);
            pw.y = (unsigned int)f2bf(p2) | ((unsigned int)f2bf(p3) << 16);
            *(uint2*)&Ps[w][cc][jt * 16 + 4 * g] = pw;
        }
        rs += __shfl_xor(rs, 16);
        rs += __shfl_xor(rs, 32);
        lrun += rs;

        asm volatile("s_waitcnt lgkmcnt(0)" ::: "memory");
        __builtin_amdgcn_sched_barrier(0);

        __builtin_amdgcn_s_setprio(1);
#pragma unroll
        for (int ks = 0; ks < 2; ++ks) {
            const short8 pa = *(const short8*)&Ps[w][cc][ks * 32 + g * 8];
#pragma unroll
            for (int nt = 0; nt < 8; ++nt) {
                const short8 vf = *(const short8*)&Vs[voff[ks] + nt * 1024];
                o[nt] = __builtin_amdgcn_mfma_f32_16x16x32_bf16(pa, vf, o[nt], 0, 0, 0);
            }
        }
        __builtin_amdgcn_s_setprio(0);
    }

#pragma unroll
    for (int nt = 0; nt < 8; ++nt)
#pragma unroll
        for (int r = 0; r < 4; ++r)
            po[((size_t)slot * 64 + w * 16 + g * 4 + r) * 128 + nt * 16 + cc] =
                f2bf(o[nt][r]);
    if (g == 0) ml[slot * 64 + w * 16 + cc] = make_float2(mrun, lrun);
}

// ---------------------------------------------------------------------------
// Kernel 3: merge 3 partials per q-row (exact r10 version).
// ---------------------------------------------------------------------------
__global__ __launch_bounds__(256) void attn_merge(const unsigned short* __restrict__ po,
                                                  const float2* __restrict__ ml,
                                                  float* __restrict__ out) {
    const int bq   = blockIdx.x;
    const int row  = threadIdx.x >> 2;
    const int cs   = (threadIdx.x & 3) * 32;
    const int slot = bq * 3;

    const float2 ml0 = ml[(size_t)(slot + 0) * 64 + row];
    const float2 ml1 = ml[(size_t)(slot + 1) * 64 + row];
    const float2 ml2 = ml[(size_t)(slot + 2) * 64 + row];
    const float M  = fmaxf(fmaxf(ml0.x, ml1.x), ml2.x);
    float e0 = __expf(ml0.x - M);
    float e1 = __expf(ml1.x - M);
    float e2 = __expf(ml2.x - M);
    const float inv = 1.f / (ml0.y * e0 + ml1.y * e1 + ml2.y * e2);
    e0 *= inv; e1 *= inv; e2 *= inv;

    const unsigned short* p0 = po + ((size_t)(slot + 0) * 64 + row) * 128 + cs;
    const unsigned short* p1 = po + ((size_t)(slot + 1) * 64 + row) * 128 + cs;
    const unsigned short* p2 = po + ((size_t)(slot + 2) * 64 + row) * 128 + cs;
    float* op = out + ((size_t)bq * 64 + row) * 128 + cs;

#pragma unroll
    for (int i = 0; i < 4; ++i) {
        const short8 a = *(const short8*)(p0 + i * 8);
        const short8 b = *(const short8*)(p1 + i * 8);
        const short8 c = *(const short8*)(p2 + i * 8);
        float4 o0, o1;
        o0.x = bf2f((unsigned short)a[0]) * e0 + bf2f((unsigned short)b[0]) * e1 + bf2f((unsigned short)c[0]) * e2;
        o0.y = bf2f((unsigned short)a[1]) * e0 + bf2f((unsigned short)b[1]) * e1 + bf2f((unsigned short)c[1]) * e2;
        o0.z = bf2f((unsigned short)a[2]) * e0 + bf2f((unsigned short)b[2]) * e1 + bf2f((unsigned short)c[2]) * e2;
        o0.w = bf2f((unsigned short)a[3]) * e0 + bf2f((unsigned short)b[3]) * e1 + bf2f((unsigned short)c[3]) * e2;
        o1.x = bf2f((unsigned short)a[4]) * e0 + bf2f((unsigned short)b[4]) * e1 + bf2f((unsigned short)c[4]) * e2;
        o1.y = bf2f((unsigned short)a[5]) * e0 + bf2f((unsigned short)b[5]) * e1 + bf2f((unsigned short)c[5]) * e2;
        o1.z = bf2f((unsigned short)a[6]) * e0 + bf2f((unsigned short)b[6]) * e1 + bf2f((unsigned short)c[6]) * e2;
        o1.w = bf2f((unsigned short)a[7]) * e0 + bf2f((unsigned short)b[7]) * e1 + bf2f((unsigned short)c[7]) * e2;
        *(float4*)(op + i * 8)     = o0;
        *(float4*)(op + i * 8 + 4) = o1;
    }
}

extern "C" void kernel_launch(void* const* d_in, const int* in_sizes, int n_in,
                              void* d_out, int out_size, void* d_ws, size_t ws_size,
                              hipStream_t stream) {
    (void)in_sizes; (void)n_in; (void)out_size; (void)ws_size;
    const float* x = (const float*)d_in[0];      // (8,2048,1024) f32
    const float* W = (const float*)d_in[1];      // (384,1024) f32
    float* out = (float*)d_out;                  // (8,2048,128) f32

    unsigned short* qkbf = (unsigned short*)d_ws;           // [16384][256] bf16
    unsigned short* vtbf = qkbf + (size_t)16384 * 256;      // [8][128][2048] bf16
    unsigned short* wtbf = vtbf + (size_t)8 * 128 * 2048;   // packed W, 768 KB
    unsigned short* pobf = wtbf + (size_t)3 * 16 * 128 * 64;         // partials o
    float2*         mlf  = (float2*)(pobf + (size_t)768 * 64 * 128); // partials m,l

    pack_w<<<dim3(192), 256, 0, stream>>>(W, wtbf);
    qkv_gemm<<<dim3(3, 256), 256, 0, stream>>>(x, wtbf, qkbf, vtbf);
    attn_part<<<dim3(96, 8), 256, 0, stream>>>(qkbf, vtbf, pobf, mlf);
    attn_merge<<<dim3(256), 256, 0, stream>>>(pobf, mlf, out);
}

// Round 18
// 64.390 us; speedup vs baseline: 1.5484x; 1.1692x over previous
//
#include <hip/hip_runtime.h>
#include <hip/hip_bf16.h>
#include <math.h>

#define D_MODEL 1024
#define TLEN    2048

typedef __attribute__((ext_vector_type(8))) short short8;
typedef __attribute__((ext_vector_type(4))) float f32x4;

static __device__ __forceinline__ unsigned short f2bf(float f) {
    __hip_bfloat16 h = __float2bfloat16(f);
    return __builtin_bit_cast(unsigned short, h);
}
static __device__ __forceinline__ float bf2f(unsigned short u) {
    unsigned int x = ((unsigned int)u) << 16;
    return __builtin_bit_cast(float, x);
}
static __device__ __forceinline__ void lds_cp16(void* lds, const void* g) {
    __builtin_amdgcn_global_load_lds(
        (const __attribute__((address_space(1))) unsigned int*)g,
        (__attribute__((address_space(3))) unsigned int*)lds, 16, 0, 0);
}

// ---------------------------------------------------------------------------
// Kernel 0 (exact r10): pack W fp32 [384][1024] -> wt bf16 [np3][kt16][h128][k64]
// swizzled (8-short k-group XOR h&7).
// ---------------------------------------------------------------------------
__global__ __launch_bounds__(256) void pack_w(const float* __restrict__ W,
                                              unsigned short* __restrict__ wt) {
    const int id = blockIdx.x * 256 + threadIdx.x;
    const int h  = id >> 7;
    const int kg = id & 127;
    const int k0 = kg * 8;
    const int kt = k0 >> 6;
    const int kin = k0 & 63;
    const int np = h >> 7;
    const int hp = h & 127;
    const float4 a = *(const float4*)&W[(size_t)h * D_MODEL + k0];
    const float4 b = *(const float4*)&W[(size_t)h * D_MODEL + k0 + 4];
    short8 v;
    v[0] = (short)f2bf(a.x); v[1] = (short)f2bf(a.y);
    v[2] = (short)f2bf(a.z); v[3] = (short)f2bf(a.w);
    v[4] = (short)f2bf(b.x); v[5] = (short)f2bf(b.y);
    v[6] = (short)f2bf(b.z); v[7] = (short)f2bf(b.w);
    const size_t dst = ((size_t)(np * 16 + kt) * 128 + hp) * 64 + (kin ^ ((hp & 7) * 8));
    *(short8*)&wt[dst] = v;
}

// ---------------------------------------------------------------------------
// Kernel 1 (exact r10, proven ~30us): BM=64, BN=128, BK=64, grid (256,3),
// 4 blocks/CU. bid = bx + 256*np and 256%8==0 -> panel siblings share an XCD
// (x tile L2-hot) — this is why this dispatch beats all variants tried.
// Q panel (np==0) pre-scaled by 1/sqrt(128).
// ---------------------------------------------------------------------------
__global__ __launch_bounds__(256, 4) void qkv_gemm(const float* __restrict__ x,
                                                   const unsigned short* __restrict__ wt,
                                                   unsigned short* __restrict__ qk,
                                                   unsigned short* __restrict__ vt) {
    __shared__ unsigned short As[64][88];
    __shared__ unsigned short Bs[128 * 64];

    const int tid  = threadIdx.x;
    const int lane = tid & 63;
    const int w    = tid >> 6;
    const int wm   = w >> 1, wn = w & 1;
    const int cc   = lane & 15, g = lane >> 4;
    const int row0 = blockIdx.x * 64;
    const int np   = blockIdx.y;

    const int xr  = tid >> 2;
    const int xc0 = (tid & 3) * 16;

    const f32x4 zero = {0.f, 0.f, 0.f, 0.f};
    f32x4 acc[2][4];
#pragma unroll
    for (int i = 0; i < 2; ++i)
#pragma unroll
        for (int j = 0; j < 4; ++j) acc[i][j] = zero;

    const float* xrow = x + (size_t)(row0 + xr) * D_MODEL + xc0;
    float4 xa[4];
#pragma unroll
    for (int i = 0; i < 4; ++i) xa[i] = *(const float4*)(xrow + i * 4);

    const unsigned short* wtile0 =
        wt + (size_t)np * 16 * 128 * 64 + (w * 4 * 1024 + lane * 16) / 2;
    unsigned short* bdst = Bs + (w * 4 * 1024) / 2;

    for (int kt = 0; kt < 16; ++kt) {
        __syncthreads();
        {
            short8 s0, s1;
            s0[0] = (short)f2bf(xa[0].x); s0[1] = (short)f2bf(xa[0].y);
            s0[2] = (short)f2bf(xa[0].z); s0[3] = (short)f2bf(xa[0].w);
            s0[4] = (short)f2bf(xa[1].x); s0[5] = (short)f2bf(xa[1].y);
            s0[6] = (short)f2bf(xa[1].z); s0[7] = (short)f2bf(xa[1].w);
            s1[0] = (short)f2bf(xa[2].x); s1[1] = (short)f2bf(xa[2].y);
            s1[2] = (short)f2bf(xa[2].z); s1[3] = (short)f2bf(xa[2].w);
            s1[4] = (short)f2bf(xa[3].x); s1[5] = (short)f2bf(xa[3].y);
            s1[6] = (short)f2bf(xa[3].z); s1[7] = (short)f2bf(xa[3].w);
            *(short8*)&As[xr][xc0]     = s0;
            *(short8*)&As[xr][xc0 + 8] = s1;
        }
        const unsigned short* wtk = wtile0 + (size_t)kt * 128 * 64;
#pragma unroll
        for (int i = 0; i < 4; ++i)
            lds_cp16(bdst + i * 512, wtk + i * 512);
        __syncthreads();

        short8 af[2][2], bf[2][4];
#pragma unroll
        for (int ks = 0; ks < 2; ++ks) {
#pragma unroll
            for (int mt = 0; mt < 2; ++mt)
                af[ks][mt] = *(const short8*)&As[wm * 32 + mt * 16 + cc][ks * 32 + g * 8];
#pragma unroll
            for (int nt = 0; nt < 4; ++nt) {
                const int h = wn * 64 + nt * 16 + cc;
                bf[ks][nt] = *(const short8*)&Bs[h * 64 + (((ks * 4 + g) ^ (h & 7)) << 3)];
            }
        }
        if (kt + 1 < 16) {
#pragma unroll
            for (int i = 0; i < 4; ++i)
                xa[i] = *(const float4*)(xrow + (kt + 1) * 64 + i * 4);
        }
        __builtin_amdgcn_s_setprio(1);
#pragma unroll
        for (int ks = 0; ks < 2; ++ks)
#pragma unroll
            for (int mt = 0; mt < 2; ++mt)
#pragma unroll
                for (int nt = 0; nt < 4; ++nt)
                    acc[mt][nt] = __builtin_amdgcn_mfma_f32_16x16x32_bf16(
                        af[ks][mt], bf[ks][nt], acc[mt][nt], 0, 0, 0);
        __builtin_amdgcn_s_setprio(0);
    }

    const int bb  = row0 >> 11;
    const int tr0 = row0 & 2047;
    const float qs = (np == 0) ? 0.08838834764831845f : 1.0f;
#pragma unroll
    for (int mt = 0; mt < 2; ++mt)
#pragma unroll
        for (int nt = 0; nt < 4; ++nt) {
            const int colp = wn * 64 + nt * 16;
            if (np < 2) {
#pragma unroll
                for (int r = 0; r < 4; ++r) {
                    const int row = row0 + wm * 32 + mt * 16 + g * 4 + r;
                    qk[(size_t)row * 256 + np * 128 + colp + cc] = f2bf(acc[mt][nt][r] * qs);
                }
            } else {
                const int d    = colp + cc;
                const int trow = tr0 + wm * 32 + mt * 16 + g * 4;
                ushort4 u;
                u.x = f2bf(acc[mt][nt][0]);
                u.y = f2bf(acc[mt][nt][1]);
                u.z = f2bf(acc[mt][nt][2]);
                u.w = f2bf(acc[mt][nt][3]);
                *(ushort4*)&vt[((size_t)(bb * 128 + d)) * TLEN + trow] = u;
            }
        }
}

// ---------------------------------------------------------------------------
// Kernel 2: attention partial (r7/r10 compute, unchanged) with XCD-BATCH
// LOCALITY: 1-D grid 768, b = bid & 7 -> each XCD owns one batch whose
// qk+vt slice (1.5 MB) is L2-resident; K/V staging becomes L2-hit.
// qtg = bid >> 3 keeps long-blocks-first (qt = 31 - qtg/3).
// ---------------------------------------------------------------------------
__global__ __launch_bounds__(256, 3) void attn_part(const unsigned short* __restrict__ qk,
                                                    const unsigned short* __restrict__ vt,
                                                    unsigned short* __restrict__ po,
                                                    float2* __restrict__ ml) {
    __shared__ unsigned short Ks[64 * 128];
    __shared__ unsigned short Vs[128 * 64];
    __shared__ unsigned short Ps[4][16][72];

    const int tid  = threadIdx.x;
    const int lane = tid & 63;
    const int w    = tid >> 6;
    const int cc   = lane & 15, g = lane >> 4;
    const int bid  = blockIdx.x;       // 0..767
    const int b    = bid & 7;          // XCD-local batch (bid%8 == XCD heuristic)
    const int qtg  = bid >> 3;         // 0..95
    const int qt   = 31 - (qtg / 3);   // long blocks first
    const int ggg  = qtg % 3;
    const int q0   = qt * 64;
    const int slot = (b * 32 + qt) * 3 + ggg;
    const int n    = qt + 1;
    const int cnt  = (n > ggg) ? ((n - ggg + 2) / 3) : 0;

    if (cnt == 0) {
#pragma unroll
        for (int nt = 0; nt < 8; ++nt)
#pragma unroll
            for (int r = 0; r < 4; ++r)
                po[((size_t)slot * 64 + w * 16 + g * 4 + r) * 128 + nt * 16 + cc] = 0;
        if (g == 0) ml[slot * 64 + w * 16 + cc] = make_float2(-INFINITY, 0.f);
        return;
    }

    short8 qf[4];
    {
        const unsigned short* qb =
            qk + ((size_t)(b * TLEN + q0 + w * 16 + cc)) * 256 + g * 8;
#pragma unroll
        for (int kt = 0; kt < 4; ++kt) qf[kt] = *(const short8*)(qb + kt * 32);
    }

    const f32x4 zero = {0.f, 0.f, 0.f, 0.f};
    f32x4 o[8];
#pragma unroll
    for (int nt = 0; nt < 8; ++nt) o[nt] = zero;
    float mrun = -INFINITY, lrun = 0.f;

    int koff[4], voff[2];
#pragma unroll
    for (int kt = 0; kt < 4; ++kt)
        koff[kt] = cc * 128 + (((kt * 4 + g) ^ (cc & 7)) << 3);
#pragma unroll
    for (int ks = 0; ks < 2; ++ks)
        voff[ks] = cc * 64 + (((ks * 4 + g) ^ (cc & 7)) << 3);

    const int kRow = tid >> 2;
    const int kG0  = (tid & 3) * 4;
    const int vRow = tid >> 1;
    const int vG0  = (tid & 1) * 4;
    const unsigned short* kgp = qk + ((size_t)(b * TLEN + kRow)) * 256 + 128 + kG0 * 8;
    const unsigned short* vgp = vt + ((size_t)(b * 128 + vRow)) * TLEN + vG0 * 8;

    short8 kr[4], vr[4];
#pragma unroll
    for (int i = 0; i < 4; ++i) kr[i] = *(const short8*)(kgp + (size_t)ggg * 16384 + i * 8);
#pragma unroll
    for (int i = 0; i < 4; ++i) vr[i] = *(const short8*)(vgp + ggg * 64 + i * 8);

    for (int s = 0; s < cnt; ++s) {
        const int t  = 3 * s + ggg;
        const int j0 = t * 64;
        __syncthreads();
#pragma unroll
        for (int i = 0; i < 4; ++i) {
            *(short8*)&Ks[kRow * 128 + (((kG0 + i) ^ (kRow & 7)) << 3)] = kr[i];
            *(short8*)&Vs[vRow * 64  + (((vG0 + i) ^ (vRow & 7)) << 3)] = vr[i];
        }
        __syncthreads();
        if (s + 1 < cnt) {
            const int tn = t + 3;
#pragma unroll
            for (int i = 0; i < 4; ++i) kr[i] = *(const short8*)(kgp + (size_t)tn * 16384 + i * 8);
#pragma unroll
            for (int i = 0; i < 4; ++i) vr[i] = *(const short8*)(vgp + tn * 64 + i * 8);
        }

        f32x4 st[4];
#pragma unroll
        for (int jt = 0; jt < 4; ++jt) st[jt] = zero;
        __builtin_amdgcn_s_setprio(1);
#pragma unroll
        for (int kt = 0; kt < 4; ++kt)
#pragma unroll
            for (int jt = 0; jt < 4; ++jt) {
                const short8 kf = *(const short8*)&Ks[koff[kt] + jt * 2048];
                st[jt] = __builtin_amdgcn_mfma_f32_16x16x32_bf16(kf, qf[kt], st[jt], 0, 0, 0);
            }
        __builtin_amdgcn_s_setprio(0);

        if (t == qt) {
            const int qg = q0 + w * 16 + cc;
            const int jb = j0 + 4 * g;
#pragma unroll
            for (int jt = 0; jt < 4; ++jt)
#pragma unroll
                for (int r = 0; r < 4; ++r)
                    if (jb + jt * 16 + r > qg) st[jt][r] = -INFINITY;
        }
        float pmax = -INFINITY;
#pragma unroll
        for (int jt = 0; jt < 4; ++jt) {
            const float a = fmaxf(st[jt][0], st[jt][1]);
            const float c = fmaxf(st[jt][2], st[jt][3]);
            pmax = fmaxf(pmax, fmaxf(a, c));
        }
        pmax = fmaxf(pmax, __shfl_xor(pmax, 16));
        pmax = fmaxf(pmax, __shfl_xor(pmax, 32));

        if (!__all(pmax <= mrun + 8.f)) {
            const float newm  = fmaxf(mrun, pmax);
            const float alpha = __expf(mrun - newm);
            mrun = newm;
            lrun *= alpha;
            float arow[4];
#pragma unroll
            for (int r = 0; r < 4; ++r) arow[r] = __shfl(alpha, 20 * g + r);
#pragma unroll
            for (int nt = 0; nt < 8; ++nt)
#pragma unroll
                for (int r = 0; r < 4; ++r) o[nt][r] *= arow[r];
        }

        float rs = 0.f;
#pragma unroll
        for (int jt = 0; jt < 4; ++jt) {
            const float p0 = __expf(st[jt][0] - mrun);
            const float p1 = __expf(st[jt][1] - mrun);
            const float p2 = __expf(st[jt][2] - mrun);
            const float p3 = __expf(st[jt][3] - mrun);
            rs += (p0 + p1) + (p2 + p3);
            uint2 pw;
            pw.x = (unsigned int)f2bf(p0) | ((unsigned int)f2bf(p1) << 16);
            pw.y = (unsigned int)f2bf(p2) | ((unsigned int)f2bf(p3) << 16);
            *(uint2*)&Ps[w][cc][jt * 16 + 4 * g] = pw;
        }
        rs += __shfl_xor(rs, 16);
        rs += __shfl_xor(rs, 32);
        lrun += rs;

        asm volatile("s_waitcnt lgkmcnt(0)" ::: "memory");
        __builtin_amdgcn_sched_barrier(0);

        __builtin_amdgcn_s_setprio(1);
#pragma unroll
        for (int ks = 0; ks < 2; ++ks) {
            const short8 pa = *(const short8*)&Ps[w][cc][ks * 32 + g * 8];
#pragma unroll
            for (int nt = 0; nt < 8; ++nt) {
                const short8 vf = *(const short8*)&Vs[voff[ks] + nt * 1024];
                o[nt] = __builtin_amdgcn_mfma_f32_16x16x32_bf16(pa, vf, o[nt], 0, 0, 0);
            }
        }
        __builtin_amdgcn_s_setprio(0);
    }

#pragma unroll
    for (int nt = 0; nt < 8; ++nt)
#pragma unroll
        for (int r = 0; r < 4; ++r)
            po[((size_t)slot * 64 + w * 16 + g * 4 + r) * 128 + nt * 16 + cc] =
                f2bf(o[nt][r]);
    if (g == 0) ml[slot * 64 + w * 16 + cc] = make_float2(mrun, lrun);
}

// ---------------------------------------------------------------------------
// Kernel 3: merge 3 partials per q-row (exact r10 version).
// ---------------------------------------------------------------------------
__global__ __launch_bounds__(256) void attn_merge(const unsigned short* __restrict__ po,
                                                  const float2* __restrict__ ml,
                                                  float* __restrict__ out) {
    const int bq   = blockIdx.x;
    const int row  = threadIdx.x >> 2;
    const int cs   = (threadIdx.x & 3) * 32;
    const int slot = bq * 3;

    const float2 ml0 = ml[(size_t)(slot + 0) * 64 + row];
    const float2 ml1 = ml[(size_t)(slot + 1) * 64 + row];
    const float2 ml2 = ml[(size_t)(slot + 2) * 64 + row];
    const float M  = fmaxf(fmaxf(ml0.x, ml1.x), ml2.x);
    float e0 = __expf(ml0.x - M);
    float e1 = __expf(ml1.x - M);
    float e2 = __expf(ml2.x - M);
    const float inv = 1.f / (ml0.y * e0 + ml1.y * e1 + ml2.y * e2);
    e0 *= inv; e1 *= inv; e2 *= inv;

    const unsigned short* p0 = po + ((size_t)(slot + 0) * 64 + row) * 128 + cs;
    const unsigned short* p1 = po + ((size_t)(slot + 1) * 64 + row) * 128 + cs;
    const unsigned short* p2 = po + ((size_t)(slot + 2) * 64 + row) * 128 + cs;
    float* op = out + ((size_t)bq * 64 + row) * 128 + cs;

#pragma unroll
    for (int i = 0; i < 4; ++i) {
        const short8 a = *(const short8*)(p0 + i * 8);
        const short8 b = *(const short8*)(p1 + i * 8);
        const short8 c = *(const short8*)(p2 + i * 8);
        float4 o0, o1;
        o0.x = bf2f((unsigned short)a[0]) * e0 + bf2f((unsigned short)b[0]) * e1 + bf2f((unsigned short)c[0]) * e2;
        o0.y = bf2f((unsigned short)a[1]) * e0 + bf2f((unsigned short)b[1]) * e1 + bf2f((unsigned short)c[1]) * e2;
        o0.z = bf2f((unsigned short)a[2]) * e0 + bf2f((unsigned short)b[2]) * e1 + bf2f((unsigned short)c[2]) * e2;
        o0.w = bf2f((unsigned short)a[3]) * e0 + bf2f((unsigned short)b[3]) * e1 + bf2f((unsigned short)c[3]) * e2;
        o1.x = bf2f((unsigned short)a[4]) * e0 + bf2f((unsigned short)b[4]) * e1 + bf2f((unsigned short)c[4]) * e2;
        o1.y = bf2f((unsigned short)a[5]) * e0 + bf2f((unsigned short)b[5]) * e1 + bf2f((unsigned short)c[5]) * e2;
        o1.z = bf2f((unsigned short)a[6]) * e0 + bf2f((unsigned short)b[6]) * e1 + bf2f((unsigned short)c[6]) * e2;
        o1.w = bf2f((unsigned short)a[7]) * e0 + bf2f((unsigned short)b[7]) * e1 + bf2f((unsigned short)c[7]) * e2;
        *(float4*)(op + i * 8)     = o0;
        *(float4*)(op + i * 8 + 4) = o1;
    }
}

extern "C" void kernel_launch(void* const* d_in, const int* in_sizes, int n_in,
                              void* d_out, int out_size, void* d_ws, size_t ws_size,
                              hipStream_t stream) {
    (void)in_sizes; (void)n_in; (void)out_size; (void)ws_size;
    const float* x = (const float*)d_in[0];      // (8,2048,1024) f32
    const float* W = (const float*)d_in[1];      // (384,1024) f32
    float* out = (float*)d_out;                  // (8,2048,128) f32

    unsigned short* qkbf = (unsigned short*)d_ws;           // [16384][256] bf16
    unsigned short* vtbf = qkbf + (size_t)16384 * 256;      // [8][128][2048] bf16
    unsigned short* wtbf = vtbf + (size_t)8 * 128 * 2048;   // packed W, 768 KB
    unsigned short* pobf = wtbf + (size_t)3 * 16 * 128 * 64;         // partials o
    float2*         mlf  = (float2*)(pobf + (size_t)768 * 64 * 128); // partials m,l

    pack_w<<<dim3(192), 256, 0, stream>>>(W, wtbf);
    qkv_gemm<<<dim3(256, 3), 256, 0, stream>>>(x, wtbf, qkbf, vtbf);
    attn_part<<<dim3(768), 256, 0, stream>>>(qkbf, vtbf, pobf, mlf);
    attn_merge<<<dim3(256), 256, 0, stream>>>(pobf, mlf, out);
}